// Round 3
// baseline (576.956 us; speedup 1.0000x reference)
//
#include <hip/hip_runtime.h>

// LocalAttention: B=4, L=4096, D=1024, H=16, hd=64, WINDOW=128, nW=32
#define M_TOK 16384
#define DM    1024

typedef __bf16 bf16x8 __attribute__((ext_vector_type(8)));
typedef float  f32x4  __attribute__((ext_vector_type(4)));
typedef unsigned short us8 __attribute__((ext_vector_type(8)));
typedef unsigned short us4 __attribute__((ext_vector_type(4)));

__device__ __forceinline__ unsigned short f2bf(float f) {
    unsigned u = __float_as_uint(f);
    u += 0x7FFFu + ((u >> 16) & 1u);   // RNE
    return (unsigned short)(u >> 16);
}

// packed f32x2 -> bf16x2 (low half = first arg)
__device__ __forceinline__ unsigned pk2bf(float a, float b) {
#if __has_builtin(__builtin_amdgcn_cvt_pk_bf16_f32)
    auto r = __builtin_amdgcn_cvt_pk_bf16_f32(a, b);
    unsigned u; __builtin_memcpy(&u, &r, 4); return u;
#else
    return (unsigned)f2bf(a) | ((unsigned)f2bf(b) << 16);
#endif
}

__device__ __forceinline__ void gl2lds16(const unsigned short* g, unsigned short* l) {
    __builtin_amdgcn_global_load_lds(
        (const __attribute__((address_space(1))) unsigned int*)g,
        (__attribute__((address_space(3))) unsigned int*)l, 16, 0, 0);
}

// Stage one 16B LDS slot from fp32 global (8 floats -> 8 bf16), using the
// same XOR chunk swizzle as the DMA path: slot s -> row r=s>>2, chunk
// c=(s&3)^((r>>1)&3); source = gsrc[r*stride + k0 + c*8 ...].
__device__ __forceinline__ void stage_f32slot(
    const float* __restrict__ gsrc, unsigned short* lds, int s, int k0)
{
    int r = s >> 2, c = (s & 3) ^ ((r >> 1) & 3);
    const float4* p = (const float4*)(gsrc + (size_t)r * DM + k0 + c * 8);
    float4 f0 = p[0], f1 = p[1];
    uint4 o;
    o.x = pk2bf(f0.x, f0.y);
    o.y = pk2bf(f0.z, f0.w);
    o.z = pk2bf(f1.x, f1.y);
    o.w = pk2bf(f1.z, f1.w);
    *(uint4*)(lds + s * 8) = o;
}

// ---------------------------------------------------------------------------
// fp32 -> bf16 stream convert (weights only now)
// ---------------------------------------------------------------------------
__global__ __launch_bounds__(256) void conv_f2b(
    const float* __restrict__ src, unsigned short* __restrict__ dst, int n8)
{
    int i = blockIdx.x * blockDim.x + threadIdx.x;
    int stride = gridDim.x * blockDim.x;
    for (; i < n8; i += stride) {
        const float4* s = (const float4*)(src + (size_t)i * 8);
        float4 a = s[0], b = s[1];
        uint4 o;
        o.x = pk2bf(a.x, a.y); o.y = pk2bf(a.z, a.w);
        o.z = pk2bf(b.x, b.y); o.w = pk2bf(b.z, b.w);
        *(uint4*)(dst + (size_t)i * 8) = o;
    }
}

// XCD-aware swizzle: hw assigns block (x + 8y [+1024z]) round-robin to XCDs
// (id%8). Remap so each XCD owns 16 contiguous m-rows with all 8 n-blocks ->
// A-tiles stay resident in that XCD's 4MB L2.
#define XCD_SWIZZLE()                                                          \
    const int fid = blockIdx.x + (blockIdx.y << 3);                            \
    const int mbase = (((fid & 7) << 4) + (fid >> 6)) << 7;                    \
    const int nbase = ((fid >> 3) & 7) << 7;

// common per-thread constants for the 128x128x32 MFMA core
#define GEMM_IDX()                                                             \
    const int tid = threadIdx.x, lane = tid & 63, wv = tid >> 6;               \
    const int wrow = (wv >> 1) * 64, wcol = (wv & 1) * 64;                     \
    const int lrow = lane & 15, qd = lane >> 4;                                \
    const int s0 = tid, s1 = tid + 256;                                        \
    const int r0 = s0 >> 2, c0 = (s0 & 3) ^ ((r0 >> 1) & 3);                   \
    const int r1 = s1 >> 2, c1 = (s1 & 3) ^ ((r1 >> 1) & 3);                   \
    const int g0 = r0 * DM + c0 * 8;                                           \
    const int g1 = r1 * DM + c1 * 8;                                           \
    int aslot[4], bslot[4];                                                    \
    _Pragma("unroll")                                                          \
    for (int i = 0; i < 4; ++i) {                                              \
        int ra = wrow + i * 16 + lrow;                                         \
        int rb = wcol + i * 16 + lrow;                                         \
        aslot[i] = ra * 32 + (qd ^ ((ra >> 1) & 3)) * 8;                       \
        bslot[i] = rb * 32 + (qd ^ ((rb >> 1) & 3)) * 8;                       \
    }

#define GEMM_MFMA_BLOCK()                                                      \
    bf16x8 af[4], bfr[4];                                                      \
    _Pragma("unroll")                                                          \
    for (int i = 0; i < 4; ++i) af[i]  = *(const bf16x8*)(As + aslot[i]);      \
    _Pragma("unroll")                                                          \
    for (int i = 0; i < 4; ++i) bfr[i] = *(const bf16x8*)(Bs + bslot[i]);      \
    _Pragma("unroll")                                                          \
    for (int i = 0; i < 4; ++i)                                                \
        _Pragma("unroll")                                                      \
        for (int j = 0; j < 4; ++j)                                            \
            acc[i][j] = __builtin_amdgcn_mfma_f32_16x16x32_bf16(               \
                af[i], bfr[j], acc[i][j], 0, 0, 0);

// ---------------------------------------------------------------------------
// QKV projection GEMM, one dispatch grid (8,128,3). A = fp32 input (converted
// during staging), W = bf16 (DMA). Epilogue writes attention layouts:
// z=0/1: C[((b*16+h)*4096+tok)*64+dh]; z=2: C[((b*16+h)*64+dh)*4096+tok].
// ---------------------------------------------------------------------------
__global__ __launch_bounds__(256) void gemm_qkv_f32(
    const float* __restrict__ qin, const float* __restrict__ kin,
    const float* __restrict__ vin, const unsigned short* __restrict__ Wb,
    const float* __restrict__ ipb, unsigned short* __restrict__ Cq,
    unsigned short* __restrict__ Ck, unsigned short* __restrict__ Cv)
{
    __shared__ unsigned short As[4096];
    __shared__ unsigned short Bs[4096];
    XCD_SWIZZLE()
    GEMM_IDX()

    const int z = blockIdx.z;
    const float* A = (z == 0) ? qin : ((z == 1) ? kin : vin);
    const unsigned short* W = Wb + (size_t)z * DM * DM;
    const float* bp = ipb + z * DM;

    const float* Ab = A + (size_t)mbase * DM;
    const unsigned short* Bb = W + (size_t)nbase * DM;

    f32x4 acc[4][4] = {};
    for (int k0 = 0; k0 < DM; k0 += 32) {
        __syncthreads();
        gl2lds16(Bb + k0 + g0, Bs + s0 * 8);
        gl2lds16(Bb + k0 + g1, Bs + s1 * 8);
        stage_f32slot(Ab, As, s0, k0);
        stage_f32slot(Ab, As, s1, k0);
        __syncthreads();
        GEMM_MFMA_BLOCK()
    }

    if (z <= 1) {
        unsigned short* C = (z == 0) ? Cq : Ck;
        #pragma unroll
        for (int j = 0; j < 4; ++j) {
            int gc = nbase + wcol + j * 16 + lrow;
            int h = gc >> 6, dh = gc & 63;
            float bv = bp[gc];
            #pragma unroll
            for (int i = 0; i < 4; ++i) {
                int gr0 = mbase + wrow + i * 16 + qd * 4;
                int b = gr0 >> 12;
                #pragma unroll
                for (int r = 0; r < 4; ++r) {
                    int tok = (gr0 + r) & 4095;
                    C[(((size_t)b * 16 + h) * 4096 + tok) * 64 + dh] =
                        f2bf(acc[i][j][r] + bv);
                }
            }
        }
    } else {
        #pragma unroll
        for (int j = 0; j < 4; ++j) {
            int gc = nbase + wcol + j * 16 + lrow;
            int h = gc >> 6, dh = gc & 63;
            float bv = bp[gc];
            #pragma unroll
            for (int i = 0; i < 4; ++i) {
                int gr0 = mbase + wrow + i * 16 + qd * 4;
                int b = gr0 >> 12, tok = gr0 & 4095;
                us4 pk;
                #pragma unroll
                for (int r = 0; r < 4; ++r) pk[r] = f2bf(acc[i][j][r] + bv);
                *(us4*)(Cv + (((size_t)b * 16 + h) * 64 + dh) * 4096 + tok) = pk;
            }
        }
    }
}

// ---------------------------------------------------------------------------
// Output projection: A = bf16 attention output (DMA), W = fp32 out_w
// (converted during staging), C = fp32 final output + bias.
// ---------------------------------------------------------------------------
__global__ __launch_bounds__(256) void gemm_bt_out(
    const unsigned short* __restrict__ Ab16, const float* __restrict__ ow,
    const float* __restrict__ ob, float* __restrict__ out)
{
    __shared__ unsigned short As[4096];
    __shared__ unsigned short Bs[4096];
    XCD_SWIZZLE()
    GEMM_IDX()

    const unsigned short* Ab = Ab16 + (size_t)mbase * DM;
    const float* Bb = ow + (size_t)nbase * DM;

    f32x4 acc[4][4] = {};
    for (int k0 = 0; k0 < DM; k0 += 32) {
        __syncthreads();
        gl2lds16(Ab + k0 + g0, As + s0 * 8);
        gl2lds16(Ab + k0 + g1, As + s1 * 8);
        stage_f32slot(Bb, Bs, s0, k0);
        stage_f32slot(Bb, Bs, s1, k0);
        __syncthreads();
        GEMM_MFMA_BLOCK()
    }

    #pragma unroll
    for (int j = 0; j < 4; ++j) {
        int gc = nbase + wcol + j * 16 + lrow;
        float bv = ob[gc];
        #pragma unroll
        for (int i = 0; i < 4; ++i) {
            int gr0 = mbase + wrow + i * 16 + qd * 4;
            #pragma unroll
            for (int r = 0; r < 4; ++r)
                out[(size_t)(gr0 + r) * DM + gc] = acc[i][j][r] + bv;
        }
    }
}

// ---------------------------------------------------------------------------
// Attention: block per (b,wi,h); Q/K/V MFMA fragments loaded DIRECTLY from
// global (per-head layouts). Only P round-trips through LDS; wave-private
// rows -> no __syncthreads.
// ---------------------------------------------------------------------------
__global__ __launch_bounds__(256) void attn_v2(
    const unsigned short* __restrict__ qh, const unsigned short* __restrict__ kh,
    const unsigned short* __restrict__ vt, unsigned short* __restrict__ aout)
{
    const int gid = blockIdx.x;
    const int h  = gid & 15;
    const int wi = (gid >> 4) & 31;
    const int b  = gid >> 9;
    const int bh = b * 16 + h;

    const unsigned short* Qp = qh + ((size_t)bh * 4096 + wi * 128) * 64;
    const unsigned short* Kp = kh + ((size_t)bh * 4096 + wi * 128) * 64;
    const unsigned short* Vp = vt + (size_t)bh * 64 * 4096 + wi * 128;

    const int tid = threadIdx.x, lane = tid & 63, wv = tid >> 6;
    const int lrow = lane & 15, qd = lane >> 4, kof = qd * 8;

    __shared__ unsigned short Ps[128 * 136];

    f32x4 acc[2][8] = {};
    #pragma unroll
    for (int ki = 0; ki < 2; ++ki) {
        bf16x8 a0 = *(const bf16x8*)(Qp + (wv * 32 +  0 + lrow) * 64 + ki * 32 + kof);
        bf16x8 a1 = *(const bf16x8*)(Qp + (wv * 32 + 16 + lrow) * 64 + ki * 32 + kof);
        #pragma unroll
        for (int ni = 0; ni < 8; ++ni) {
            bf16x8 bb = *(const bf16x8*)(Kp + (ni * 16 + lrow) * 64 + ki * 32 + kof);
            acc[0][ni] = __builtin_amdgcn_mfma_f32_16x16x32_bf16(a0, bb, acc[0][ni], 0, 0, 0);
            acc[1][ni] = __builtin_amdgcn_mfma_f32_16x16x32_bf16(a1, bb, acc[1][ni], 0, 0, 0);
        }
    }

    const float scale = 0.125f;
    #pragma unroll
    for (int mi = 0; mi < 2; ++mi) {
        #pragma unroll
        for (int r = 0; r < 4; ++r) {
            float sc[8];
            float mx = -3.4e38f;
            #pragma unroll
            for (int ni = 0; ni < 8; ++ni) { sc[ni] = acc[mi][ni][r] * scale; mx = fmaxf(mx, sc[ni]); }
            mx = fmaxf(mx, __shfl_xor(mx, 1));
            mx = fmaxf(mx, __shfl_xor(mx, 2));
            mx = fmaxf(mx, __shfl_xor(mx, 4));
            mx = fmaxf(mx, __shfl_xor(mx, 8));
            float sum = 0.f;
            #pragma unroll
            for (int ni = 0; ni < 8; ++ni) { sc[ni] = __expf(sc[ni] - mx); sum += sc[ni]; }
            sum += __shfl_xor(sum, 1);
            sum += __shfl_xor(sum, 2);
            sum += __shfl_xor(sum, 4);
            sum += __shfl_xor(sum, 8);
            float inv = 1.0f / sum;
            #pragma unroll
            for (int ni = 0; ni < 8; ++ni) acc[mi][ni][r] = sc[ni] * inv;
        }
    }

    #pragma unroll
    for (int mi = 0; mi < 2; ++mi)
        #pragma unroll
        for (int ni = 0; ni < 8; ++ni)
            #pragma unroll
            for (int r = 0; r < 4; ++r)
                Ps[(wv * 32 + mi * 16 + qd * 4 + r) * 136 + ni * 16 + lrow] =
                    f2bf(acc[mi][ni][r]);

    f32x4 o[2][4] = {};
    #pragma unroll
    for (int kj = 0; kj < 4; ++kj) {
        bf16x8 a0 = *(const bf16x8*)(Ps + (wv * 32 +  0 + lrow) * 136 + kj * 32 + kof);
        bf16x8 a1 = *(const bf16x8*)(Ps + (wv * 32 + 16 + lrow) * 136 + kj * 32 + kof);
        #pragma unroll
        for (int nd = 0; nd < 4; ++nd) {
            bf16x8 bb = *(const bf16x8*)(Vp + (size_t)(nd * 16 + lrow) * 4096 + kj * 32 + kof);
            o[0][nd] = __builtin_amdgcn_mfma_f32_16x16x32_bf16(a0, bb, o[0][nd], 0, 0, 0);
            o[1][nd] = __builtin_amdgcn_mfma_f32_16x16x32_bf16(a1, bb, o[1][nd], 0, 0, 0);
        }
    }

    #pragma unroll
    for (int mi = 0; mi < 2; ++mi)
        #pragma unroll
        for (int nd = 0; nd < 4; ++nd)
            #pragma unroll
            for (int r = 0; r < 4; ++r) {
                int R = wv * 32 + mi * 16 + qd * 4 + r;
                int c = h * 64 + nd * 16 + lrow;
                aout[(size_t)(b * 4096 + wi * 128 + R) * DM + c] = f2bf(o[mi][nd][r]);
            }
}

// ---------------------------------------------------------------------------
extern "C" void kernel_launch(void* const* d_in, const int* in_sizes, int n_in,
                              void* d_out, int out_size, void* d_ws, size_t ws_size,
                              hipStream_t stream) {
    const float* q   = (const float*)d_in[0];
    const float* k   = (const float*)d_in[1];
    const float* v   = (const float*)d_in[2];
    const float* ipw = (const float*)d_in[3];
    const float* ipb = (const float*)d_in[4];
    const float* ow  = (const float*)d_in[5];
    const float* ob  = (const float*)d_in[6];
    float* out = (float*)d_out;

    const size_t MD = (size_t)M_TOK * DM;
    const size_t WW = (size_t)DM * DM;

    // ws layout (total (4*MD + 3*WW)*2 = 140.5 MB, proven to fit in round 2):
    unsigned short* qh   = (unsigned short*)d_ws;   // MD
    unsigned short* kh   = qh + MD;                 // MD
    unsigned short* vtb  = qh + 2 * MD;             // MD
    unsigned short* aout = qh + 3 * MD;             // MD
    unsigned short* Wb   = qh + 4 * MD;             // 3*WW (bf16 in_proj_w)

    conv_f2b<<<1536, 256, 0, stream>>>(ipw, Wb, (int)(3 * WW / 8));
    gemm_qkv_f32<<<dim3(8, 128, 3), 256, 0, stream>>>(q, k, v, Wb, ipb, qh, kh, vtb);
    attn_v2<<<2048, 256, 0, stream>>>(qh, kh, vtb, aout);
    gemm_bt_out<<<dim3(8, 128), 256, 0, stream>>>(aout, ow, ob, out);
}